// Round 1
// baseline (659.444 us; speedup 1.0000x reference)
//
#include <hip/hip_runtime.h>
#include <math.h>

// GeomAttention: B=2, L=S=2048, H=8, E=D=32, fp32.
// scores = (0.5*dot - 0.5*relu(qn2*kn2 - dot^2)) / sqrt(E); softmax over S; out = attn @ V.

#define NB 2
#define NL 2048
#define NS 2048
#define NH 8
#define NE 32
#define ND 32
#define QT 64              // queries per block
#define NWAVE 4
#define KW (NS / NWAVE)    // 512 keys per wave
#define CH 8               // chunk size for online softmax rescale amortization

// 0.5 * (1/sqrt(32)) * log2(e): softmax computed in base-2 domain.
#define CSC (0.5f * 0.17677669529663687f * 1.4426950408889634f)

__global__ __launch_bounds__(256) void kn2_kernel(const float* __restrict__ K,
                                                  float* __restrict__ KN2) {
    int tid = blockIdx.x * blockDim.x + threadIdx.x;  // (b*NS+s)*NH + h
    const float* kp = K + (size_t)tid * NE;
    float s = 0.f;
#pragma unroll
    for (int e = 0; e < NE; e += 4) {
        float4 t = *(const float4*)(kp + e);
        s = fmaf(t.x, t.x, s);
        s = fmaf(t.y, t.y, s);
        s = fmaf(t.z, t.z, s);
        s = fmaf(t.w, t.w, s);
    }
    KN2[tid] = s;
}

__global__ __launch_bounds__(256, 2) void geom_attn_kernel(
    const float* __restrict__ Q, const float* __restrict__ K,
    const float* __restrict__ V, const float* __restrict__ KN2,
    float* __restrict__ O) {
    // per-wave partials for cross-wave (split-K) softmax combine
    __shared__ float lds_acc[NWAVE][QT][ND + 1];  // +1 pad: conflict-free combine reads
    __shared__ float lds_m[NWAVE][QT];
    __shared__ float lds_l[NWAVE][QT];

    const int lane = threadIdx.x & 63;
    const int wave = threadIdx.x >> 6;
    const int qt = blockIdx.x & 31;   // 32 query tiles per (b,h)
    const int bh = blockIdx.x >> 5;   // 0..15
    const int b = bh >> 3;
    const int h = bh & 7;
    const int ql = qt * QT + lane;

    // ---- load this thread's query row into registers ----
    const float* qp = Q + (((size_t)b * NL + ql) * NH + h) * NE;
    float qreg[NE];
#pragma unroll
    for (int e = 0; e < NE; e += 4) {
        float4 t = *(const float4*)(qp + e);
        qreg[e] = t.x; qreg[e + 1] = t.y; qreg[e + 2] = t.z; qreg[e + 3] = t.w;
    }
    float qn2 = 0.f;
#pragma unroll
    for (int e = 0; e < NE; e++) qn2 = fmaf(qreg[e], qreg[e], qn2);

    const float* kbase = K + (size_t)b * NS * NH * NE + (size_t)h * NE;
    const float* vbase = V + (size_t)b * NS * NH * ND + (size_t)h * ND;
    const float* kn2base = KN2 + (size_t)b * NS * NH + h;

    float m = -INFINITY;
    float lsum = 0.f;
    float acc[ND];
#pragma unroll
    for (int d = 0; d < ND; d++) acc[d] = 0.f;

    const int s0 = wave * KW;
    for (int c = 0; c < KW; c += CH) {
        float sc[CH];
#pragma unroll
        for (int j = 0; j < CH; j++) {
            const int s = s0 + c + j;
            const float* kp = kbase + (size_t)s * NH * NE;
            float dot = 0.f;
#pragma unroll
            for (int e = 0; e < NE; e += 4) {
                float4 t = *(const float4*)(kp + e);
                dot = fmaf(t.x, qreg[e], dot);
                dot = fmaf(t.y, qreg[e + 1], dot);
                dot = fmaf(t.z, qreg[e + 2], dot);
                dot = fmaf(t.w, qreg[e + 3], dot);
            }
            const float qk2 = qn2 * kn2base[(size_t)s * NH];
            float wedge = fmaf(-dot, dot, qk2);
            wedge = fmaxf(wedge, 0.f);
            sc[j] = (dot - wedge) * CSC;  // base-2 log-domain score
        }
        // chunk-local max, one rescale per chunk
        float lm = sc[0];
#pragma unroll
        for (int j = 1; j < CH; j++) lm = fmaxf(lm, sc[j]);
        const float mn = fmaxf(m, lm);
        const float scl = __builtin_amdgcn_exp2f(m - mn);  // 0 on first chunk (m=-inf)
        lsum *= scl;
#pragma unroll
        for (int d = 0; d < ND; d++) acc[d] *= scl;
#pragma unroll
        for (int j = 0; j < CH; j++) {
            const int s = s0 + c + j;
            const float p = __builtin_amdgcn_exp2f(sc[j] - mn);
            lsum += p;
            const float* vp = vbase + (size_t)s * NH * ND;
#pragma unroll
            for (int d = 0; d < ND; d += 4) {
                float4 t = *(const float4*)(vp + d);
                acc[d]     = fmaf(p, t.x, acc[d]);
                acc[d + 1] = fmaf(p, t.y, acc[d + 1]);
                acc[d + 2] = fmaf(p, t.z, acc[d + 2]);
                acc[d + 3] = fmaf(p, t.w, acc[d + 3]);
            }
        }
        m = mn;
    }

    // ---- write per-wave partials ----
    lds_m[wave][lane] = m;
    lds_l[wave][lane] = lsum;
#pragma unroll
    for (int d = 0; d < ND; d++) lds_acc[wave][lane][d] = acc[d];
    __syncthreads();

    // ---- combine: thread handles query (tid>>2), d-range (tid&3)*8 ----
    const int qi = threadIdx.x >> 2;
    const int sub = threadIdx.x & 3;
    float mf = lds_m[0][qi];
#pragma unroll
    for (int w = 1; w < NWAVE; w++) mf = fmaxf(mf, lds_m[w][qi]);
    float sclw[NWAVE];
    float lf = 0.f;
#pragma unroll
    for (int w = 0; w < NWAVE; w++) {
        sclw[w] = __builtin_amdgcn_exp2f(lds_m[w][qi] - mf);
        lf = fmaf(lds_l[w][qi], sclw[w], lf);
    }
    const float inv = 1.0f / lf;
    float o[8];
#pragma unroll
    for (int dd = 0; dd < 8; dd++) {
        float sum = 0.f;
#pragma unroll
        for (int w = 0; w < NWAVE; w++)
            sum = fmaf(lds_acc[w][qi][sub * 8 + dd], sclw[w], sum);
        o[dd] = sum * inv;
    }
    const int qout = qt * QT + qi;
    float* op = O + (((size_t)b * NL + qout) * NH + h) * ND + sub * 8;
    *(float4*)(op) = make_float4(o[0], o[1], o[2], o[3]);
    *(float4*)(op + 4) = make_float4(o[4], o[5], o[6], o[7]);
}

extern "C" void kernel_launch(void* const* d_in, const int* in_sizes, int n_in,
                              void* d_out, int out_size, void* d_ws, size_t ws_size,
                              hipStream_t stream) {
    const float* Q = (const float*)d_in[0];
    const float* K = (const float*)d_in[1];
    const float* V = (const float*)d_in[2];
    float* O = (float*)d_out;
    float* KN2 = (float*)d_ws;  // NB*NS*NH floats = 128 KB scratch

    kn2_kernel<<<(NB * NS * NH) / 256, 256, 0, stream>>>(K, KN2);
    geom_attn_kernel<<<NB * NH * (NL / QT), 256, 0, stream>>>(Q, K, V, KN2, O);
}

// Round 2
// 144.774 us; speedup vs baseline: 4.5550x; 4.5550x over previous
//
#include <hip/hip_runtime.h>
#include <math.h>

// GeomAttention: B=2, L=S=2048, H=8, E=D=32, fp32 in/out.
// scores = (0.5*dot - 0.5*relu(qn2*kn2 - dot^2)) / sqrt(E); softmax over S; out = attn @ V.
// MFMA bf16 hi/lo-split flash-attention. 16x16x32 bf16 MFMA:
//   A-frag: A[m=lane&15][k=(lane>>4)*8+j]   B-frag: B[k=(lane>>4)*8+j][n=lane&15]
//   C/D:    C[row=(lane>>4)*4+r][col=lane&15]

#define NB 2
#define NL 2048
#define NS 2048
#define NH 8
#define NE 32
#define ND 32
#define KT 32             // keys per tile
#define NSTEP (NS / KT)   // 64

// 0.5 * (1/sqrt(32)) * log2(e): softmax in base-2 log domain.
#define CSC 0.12751742f

typedef float f32x4 __attribute__((ext_vector_type(4)));
typedef short s16x8 __attribute__((ext_vector_type(8)));
typedef unsigned short u16;
typedef u16 u16x4 __attribute__((ext_vector_type(4)));

__device__ inline u16 f2bf(float f) {  // fp32 -> bf16 RNE
    unsigned u = __float_as_uint(f);
    return (u16)((u + 0x7FFFu + ((u >> 16) & 1u)) >> 16);
}
__device__ inline float bf2f(u16 h) { return __uint_as_float(((unsigned)h) << 16); }

// 16-lane row reductions on the VALU pipe via DPP (no DS traffic).
template <int CTRL>
__device__ inline float dpp_max(float x) {
    return fmaxf(x, __int_as_float(__builtin_amdgcn_mov_dpp(__float_as_int(x), CTRL, 0xF, 0xF, false)));
}
template <int CTRL>
__device__ inline float dpp_add(float x) {
    return x + __int_as_float(__builtin_amdgcn_mov_dpp(__float_as_int(x), CTRL, 0xF, 0xF, false));
}
__device__ inline float row_reduce_max(float x) {
    x = dpp_max<0xB1>(x);    // quad_perm [1,0,3,2]  (xor 1)
    x = dpp_max<0x4E>(x);    // quad_perm [2,3,0,1]  (xor 2)
    x = dpp_max<0x124>(x);   // row_ror:4
    x = dpp_max<0x128>(x);   // row_ror:8
    return x;
}
__device__ inline float row_reduce_add(float x) {
    x = dpp_add<0xB1>(x);
    x = dpp_add<0x4E>(x);
    x = dpp_add<0x124>(x);
    x = dpp_add<0x128>(x);
    return x;
}

// kn2[b][h][s] (transposed so main kernel reads are s-contiguous)
__global__ __launch_bounds__(256) void kn2_kernel(const float* __restrict__ K,
                                                  float* __restrict__ KN2t) {
    int tid = blockIdx.x * blockDim.x + threadIdx.x;  // (b*NS+s)*NH + h
    const float* kp = K + (size_t)tid * NE;
    float s = 0.f;
#pragma unroll
    for (int e = 0; e < NE; e += 4) {
        float4 t = *(const float4*)(kp + e);
        s = fmaf(t.x, t.x, s);
        s = fmaf(t.y, t.y, s);
        s = fmaf(t.z, t.z, s);
        s = fmaf(t.w, t.w, s);
    }
    const int h = tid & 7, srow = (tid >> 3) & 2047, b = tid >> 14;
    KN2t[((size_t)(b * NH + h)) * NS + srow] = s;
}

__global__ __launch_bounds__(256) void geom_attn_mfma(
    const float* __restrict__ Q, const float* __restrict__ K,
    const float* __restrict__ V, const float* __restrict__ KN2t,
    float* __restrict__ O) {
    __shared__ u16 sKh[KT][32];       // K-tile hi  [s][e]
    __shared__ u16 sKl[KT][32];       // K-tile lo  [s][e]
    __shared__ u16 sVt[32][40];       // V-tile transposed [d][s], padded stride
    __shared__ u16 sP[4][16][40];     // per-wave P [q][s], padded stride
    __shared__ float sqn2[4][16];

    const int T = threadIdx.x;
    const int lane = T & 63, wave = T >> 6;
    const int g = lane >> 4, lc = lane & 15;
    const int g8 = g * 8;
    const int qt = blockIdx.x & 31;
    const int bh = blockIdx.x >> 5;
    const int b = bh >> 3, h = bh & 7;
    const int qw = qt * 64 + wave * 16;   // wave's 16-query base

    // ---- Q fragments (hi/lo bf16) + exact fp32 qn2 ----
    const float* qrow = Q + (((size_t)(b * NL + qw + lc) * NH + h) * NE) + g8;
    float q8[8];
    {
        float4 a = *(const float4*)qrow;
        float4 c = *(const float4*)(qrow + 4);
        q8[0] = a.x; q8[1] = a.y; q8[2] = a.z; q8[3] = a.w;
        q8[4] = c.x; q8[5] = c.y; q8[6] = c.z; q8[7] = c.w;
    }
    s16x8 qh, ql;
    float qn2p = 0.f;
#pragma unroll
    for (int i = 0; i < 8; i++) {
        u16 hh = f2bf(q8[i]);
        qh[i] = (short)hh;
        ql[i] = (short)f2bf(q8[i] - bf2f(hh));
        qn2p = fmaf(q8[i], q8[i], qn2p);
    }
    qn2p += __shfl_xor(qn2p, 16);
    qn2p += __shfl_xor(qn2p, 32);
    if (lane < 16) sqn2[wave][lc] = qn2p;       // row lc's qn2
    __builtin_amdgcn_s_waitcnt(0xC07F);         // lgkmcnt(0): same-wave LDS ordering
    float qn2r[4];
    {
        f32x4 t4 = *(f32x4*)&sqn2[wave][4 * g];
        qn2r[0] = t4[0]; qn2r[1] = t4[1]; qn2r[2] = t4[2]; qn2r[3] = t4[3];
    }

    // ---- staging roles (block-cooperative, coalesced) ----
    const int sk = T >> 3, ek = (T & 7) * 4;   // K: row sk, e-chunk ek
    const int dv = T & 31, sv = (T >> 5) * 4;  // V: column dv, s-chunk sv (transposed read)
    const float* kptr0 = K + ((size_t)(b * NS) * NH + h) * NE + (size_t)sk * (NH * NE) + ek;
    const float* vptr0 = V + ((size_t)(b * NS) * NH + h) * ND + (size_t)sv * (NH * ND) + dv;
    const float* kn2p = KN2t + (size_t)(b * NH + h) * NS;

    // ---- prefetch tile 0 into registers ----
    float4 kreg = *(const float4*)kptr0;
    float vr0 = vptr0[0], vr1 = vptr0[256], vr2 = vptr0[512], vr3 = vptr0[768];
    float kn2n0 = kn2p[lc], kn2n1 = kn2p[lc + 16];

    f32x4 acc0 = {0.f, 0.f, 0.f, 0.f}, acc1 = {0.f, 0.f, 0.f, 0.f};
    float m[4], l[4];
#pragma unroll
    for (int r = 0; r < 4; r++) { m[r] = -INFINITY; l[r] = 0.f; }

    for (int t = 0; t < NSTEP; ++t) {
        // ---- write staged tile t to LDS (cvt to bf16 hi/lo) ----
        u16x4 khv, klv, vtv;
        {
            float kx[4] = {kreg.x, kreg.y, kreg.z, kreg.w};
#pragma unroll
            for (int i = 0; i < 4; i++) {
                u16 hh = f2bf(kx[i]);
                khv[i] = hh;
                klv[i] = f2bf(kx[i] - bf2f(hh));
            }
            vtv[0] = f2bf(vr0); vtv[1] = f2bf(vr1); vtv[2] = f2bf(vr2); vtv[3] = f2bf(vr3);
        }
        *(u16x4*)&sKh[sk][ek] = khv;
        *(u16x4*)&sKl[sk][ek] = klv;
        *(u16x4*)&sVt[dv][sv] = vtv;
        const float kn2c0 = kn2n0, kn2c1 = kn2n1;

        // ---- prefetch tile t+1 (covers the compute phase) ----
        const int tn = (t + 1 < NSTEP) ? t + 1 : t;
        const size_t off = (size_t)tn * KT * (NH * NE);  // 8192 floats/tile for K and V
        kreg = *(const float4*)(kptr0 + off);
        vr0 = vptr0[off]; vr1 = vptr0[off + 256]; vr2 = vptr0[off + 512]; vr3 = vptr0[off + 768];
        kn2n0 = kn2p[tn * KT + lc]; kn2n1 = kn2p[tn * KT + 16 + lc];

        __syncthreads();  // staged tile visible

        // ---- QK^T: 3-MFMA hi/lo split per 16-key subtile ----
        s16x8 kh0 = *(s16x8*)&sKh[lc][g8];
        s16x8 kh1 = *(s16x8*)&sKh[lc + 16][g8];
        s16x8 kl0 = *(s16x8*)&sKl[lc][g8];
        s16x8 kl1 = *(s16x8*)&sKl[lc + 16][g8];
        const f32x4 z = {0.f, 0.f, 0.f, 0.f};
        f32x4 d0 = __builtin_amdgcn_mfma_f32_16x16x32_bf16(qh, kl0, z, 0, 0, 0);
        d0 = __builtin_amdgcn_mfma_f32_16x16x32_bf16(ql, kh0, d0, 0, 0, 0);
        d0 = __builtin_amdgcn_mfma_f32_16x16x32_bf16(qh, kh0, d0, 0, 0, 0);
        f32x4 d1 = __builtin_amdgcn_mfma_f32_16x16x32_bf16(qh, kl1, z, 0, 0, 0);
        d1 = __builtin_amdgcn_mfma_f32_16x16x32_bf16(ql, kh1, d1, 0, 0, 0);
        d1 = __builtin_amdgcn_mfma_f32_16x16x32_bf16(qh, kh1, d1, 0, 0, 0);

        // ---- scores (log2 domain) ----
        float sc0[4], sc1[4];
#pragma unroll
        for (int r = 0; r < 4; r++) {
            float dd = d0[r];
            float w = fmaxf(fmaf(-dd, dd, qn2r[r] * kn2c0), 0.f);
            sc0[r] = (dd - w) * CSC;
            dd = d1[r];
            w = fmaxf(fmaf(-dd, dd, qn2r[r] * kn2c1), 0.f);
            sc1[r] = (dd - w) * CSC;
        }

        // ---- online softmax (row stats via DPP over the 16-lane group) ----
        float p0[4], p1[4];
#pragma unroll
        for (int r = 0; r < 4; r++) {
            float rm = row_reduce_max(fmaxf(sc0[r], sc1[r]));
            const float nm = fmaxf(m[r], rm);
            const float al = __builtin_amdgcn_exp2f(m[r] - nm);  // 0 on first tile
            m[r] = nm;
            p0[r] = __builtin_amdgcn_exp2f(sc0[r] - nm);
            p1[r] = __builtin_amdgcn_exp2f(sc1[r] - nm);
            const float rs = row_reduce_add(p0[r] + p1[r]);
            l[r] = fmaf(l[r], al, rs);
            acc0[r] *= al;
            acc1[r] *= al;
        }

        // ---- P: C-layout -> A-layout via per-wave LDS round-trip ----
#pragma unroll
        for (int r = 0; r < 4; r++) {
            sP[wave][4 * g + r][lc] = f2bf(p0[r]);
            sP[wave][4 * g + r][lc + 16] = f2bf(p1[r]);
        }
        __builtin_amdgcn_s_waitcnt(0xC07F);  // lgkmcnt(0): same-wave write->read
        s16x8 pa = *(s16x8*)&sP[wave][lc][g8];
        s16x8 vb0 = *(s16x8*)&sVt[lc][g8];
        s16x8 vb1 = *(s16x8*)&sVt[lc + 16][g8];
        acc0 = __builtin_amdgcn_mfma_f32_16x16x32_bf16(pa, vb0, acc0, 0, 0, 0);
        acc1 = __builtin_amdgcn_mfma_f32_16x16x32_bf16(pa, vb1, acc1, 0, 0, 0);

        __syncthreads();  // compute done before next tile overwrites LDS
    }

    // ---- epilogue ----
#pragma unroll
    for (int r = 0; r < 4; r++) {
        const float inv = 1.f / l[r];
        float* op = O + (((size_t)(b * NL + qw + 4 * g + r) * NH + h) * ND);
        op[lc] = acc0[r] * inv;
        op[lc + 16] = acc1[r] * inv;
    }
}

extern "C" void kernel_launch(void* const* d_in, const int* in_sizes, int n_in,
                              void* d_out, int out_size, void* d_ws, size_t ws_size,
                              hipStream_t stream) {
    const float* Q = (const float*)d_in[0];
    const float* K = (const float*)d_in[1];
    const float* V = (const float*)d_in[2];
    float* O = (float*)d_out;
    float* KN2t = (float*)d_ws;  // NB*NH*NS floats = 64 KB scratch

    kn2_kernel<<<(NB * NS * NH) / 256, 256, 0, stream>>>(K, KN2t);
    geom_attn_mfma<<<NB * NH * (NL / 64), 256, 0, stream>>>(Q, K, V, KN2t, O);
}

// Round 3
// 136.465 us; speedup vs baseline: 4.8323x; 1.0609x over previous
//
#include <hip/hip_runtime.h>
#include <hip/hip_bf16.h>
#include <math.h>

// GeomAttention: B=2, L=S=2048, H=8, E=D=32, fp32 in/out.
// scores = (0.5*dot - 0.5*relu(qn2*kn2 - dot^2))/sqrt(E); softmax over S; out = attn @ V.
// bf16 hi/lo-split MFMA flash-attention, in-block split-K (2 halves x 4 waves),
// KT=64 key tiles, packed bf16 cvt, fused kn2, permuted-k PV staging.

#define NB 2
#define NL 2048
#define NS 2048
#define NH 8
#define NE 32
#define ND 32
#define KT 64
#define HK 1024            // keys per half-block sweep
#define NTILE (HK / KT)    // 16
#define CSC 0.12751742f    // 0.5 / sqrt(32) * log2(e)

typedef float f32x4 __attribute__((ext_vector_type(4)));
typedef short s16x8 __attribute__((ext_vector_type(8)));
typedef unsigned short u16;

__device__ inline unsigned pk2(float a, float b) {  // bf16(a) | bf16(b)<<16, RNE
    __hip_bfloat162 t = __float22bfloat162_rn(make_float2(a, b));
    union { __hip_bfloat162 h; unsigned u; } cv;
    cv.h = t;
    return cv.u;
}

template <int CTRL>
__device__ inline float dpp_max(float x) {
    return fmaxf(x, __int_as_float(__builtin_amdgcn_mov_dpp(__float_as_int(x), CTRL, 0xF, 0xF, false)));
}
template <int CTRL>
__device__ inline float dpp_add(float x) {
    return x + __int_as_float(__builtin_amdgcn_mov_dpp(__float_as_int(x), CTRL, 0xF, 0xF, false));
}
__device__ inline float row_reduce_max(float x) {  // over 16-lane group
    x = dpp_max<0xB1>(x);   // quad_perm xor1
    x = dpp_max<0x4E>(x);   // quad_perm xor2
    x = dpp_max<0x124>(x);  // row_ror:4
    x = dpp_max<0x128>(x);  // row_ror:8
    return x;
}
__device__ inline float row_reduce_add(float x) {
    x = dpp_add<0xB1>(x);
    x = dpp_add<0x4E>(x);
    x = dpp_add<0x124>(x);
    x = dpp_add<0x128>(x);
    return x;
}

__global__ __launch_bounds__(512, 4) void geom_attn(
    const float* __restrict__ Q, const float* __restrict__ K,
    const float* __restrict__ V, float* __restrict__ O) {
    // Staging LDS (reused as combine scratch after the sweep)
    __shared__ union {
        struct {
            u16 Kh[2][KT][40];   // [half][key][e], pad 40: 2-way only
            u16 Kl[2][KT][40];
            u16 Vt[2][ND][72];   // [half][d][pi(key)], pad 72
        } s;
        struct {
            float acc[8][16][33];  // [wave][q][d]
            float m[8][16];
            float l[8][16];
        } c;
    } u;
    __shared__ u16 sP[8][16][72];    // per-wave P round-trip, [q][pi(key)]
    __shared__ float skn2[2][KT];
    __shared__ float sqn2[8][16];

    const int T = threadIdx.x;
    const int lane = T & 63, wave = T >> 6;
    const int g = lane >> 4, lc = lane & 15, g8 = g * 8;
    const int half = wave >> 2;      // which key half this wave sweeps
    const int qt = blockIdx.x & 31;
    const int bh = blockIdx.x >> 5;
    const int b = bh >> 3, h = bh & 7;
    const int qw = qt * 64 + (wave & 3) * 16;

    // ---- Q fragments (hi/lo bf16) + exact qn2 ----
    const float* qrow = Q + ((size_t)((b * NL + qw + lc) * NH + h)) * NE + g8;
    float4 qa = *(const float4*)qrow, qb = *(const float4*)(qrow + 4);
    float q8[8] = {qa.x, qa.y, qa.z, qa.w, qb.x, qb.y, qb.z, qb.w};
    union { unsigned u4[4]; s16x8 v; } qh_, ql_;
    float qn2p = 0.f;
#pragma unroll
    for (int i = 0; i < 4; i++) {
        float x0 = q8[2 * i], x1 = q8[2 * i + 1];
        qn2p = fmaf(x0, x0, qn2p);
        qn2p = fmaf(x1, x1, qn2p);
        unsigned h01 = pk2(x0, x1);
        qh_.u4[i] = h01;
        float h0 = __uint_as_float(h01 << 16);
        float h1 = __uint_as_float(h01 & 0xffff0000u);
        ql_.u4[i] = pk2(x0 - h0, x1 - h1);
    }
    const s16x8 qh = qh_.v, ql = ql_.v;
    qn2p += __shfl_xor(qn2p, 16);
    qn2p += __shfl_xor(qn2p, 32);
    if (lane < 16) sqn2[wave][lc] = qn2p;
    __builtin_amdgcn_s_waitcnt(0xC07F);  // lgkmcnt(0): same-wave LDS write->read
    float qn2r[4];
#pragma unroll
    for (int r = 0; r < 4; r++) qn2r[r] = sqn2[wave][4 * g + r];

    // ---- staging roles (256 threads per half) ----
    const int Tl = T & 255;
    const int sk = Tl >> 2, ek = (Tl & 3) * 8;    // K: row sk, 8-float chunk ek
    const int dv = Tl & 31, lcv = (Tl >> 5) * 2;  // V: column dv, lc-pair lcv
    const float* kbase = K + ((size_t)(b * NS * NH) + h) * NE;
    const float* vbase = V + ((size_t)(b * NS * NH) + h) * ND;

    // ---- prefetch tile 0 ----
    int s0 = half * HK;
    float4 ka = *(const float4*)(kbase + (size_t)(s0 + sk) * 256 + ek);
    float4 kb = *(const float4*)(kbase + (size_t)(s0 + sk) * 256 + ek + 4);
    float vr[2][4];
#pragma unroll
    for (int li = 0; li < 2; li++)
#pragma unroll
        for (int si = 0; si < 4; si++)
            vr[li][si] = vbase[(size_t)(s0 + 16 * si + lcv + li) * 256 + dv];

    f32x4 acc0 = {0.f, 0.f, 0.f, 0.f}, acc1 = {0.f, 0.f, 0.f, 0.f};
    float m[4], l[4];
#pragma unroll
    for (int r = 0; r < 4; r++) { m[r] = -INFINITY; l[r] = 0.f; }

    for (int t = 0; t < NTILE; ++t) {
        // ---- stage tile t (packed bf16 hi/lo) + fused kn2 ----
        {
            float kx[8] = {ka.x, ka.y, ka.z, ka.w, kb.x, kb.y, kb.z, kb.w};
            unsigned hh[4], ll[4];
            float kn2p = 0.f;
#pragma unroll
            for (int i = 0; i < 4; i++) {
                float x0 = kx[2 * i], x1 = kx[2 * i + 1];
                kn2p = fmaf(x0, x0, kn2p);
                kn2p = fmaf(x1, x1, kn2p);
                unsigned h01 = pk2(x0, x1);
                hh[i] = h01;
                float h0 = __uint_as_float(h01 << 16);
                float h1 = __uint_as_float(h01 & 0xffff0000u);
                ll[i] = pk2(x0 - h0, x1 - h1);
            }
            *(uint4*)&u.s.Kh[half][sk][ek] = make_uint4(hh[0], hh[1], hh[2], hh[3]);
            *(uint4*)&u.s.Kl[half][sk][ek] = make_uint4(ll[0], ll[1], ll[2], ll[3]);
            kn2p = dpp_add<0xB1>(kn2p);  // quad reduce: 4 threads cover one K row
            kn2p = dpp_add<0x4E>(kn2p);
            if ((Tl & 3) == 0) skn2[half][sk] = kn2p;
#pragma unroll
            for (int li = 0; li < 2; li++) {
                unsigned v01 = pk2(vr[li][0], vr[li][1]);
                unsigned v23 = pk2(vr[li][2], vr[li][3]);
                *(uint2*)&u.s.Vt[half][dv][4 * (lcv + li)] = make_uint2(v01, v23);
            }
        }
        // ---- prefetch tile t+1 ----
        const int tn = (t + 1 < NTILE) ? t + 1 : t;
        const int sn = half * HK + tn * KT;
        ka = *(const float4*)(kbase + (size_t)(sn + sk) * 256 + ek);
        kb = *(const float4*)(kbase + (size_t)(sn + sk) * 256 + ek + 4);
#pragma unroll
        for (int li = 0; li < 2; li++)
#pragma unroll
            for (int si = 0; si < 4; si++)
                vr[li][si] = vbase[(size_t)(sn + 16 * si + lcv + li) * 256 + dv];

        __syncthreads();

        // ---- QK^T: 4 subtiles x 3-MFMA hi/lo split ----
        float kn2v[4];
#pragma unroll
        for (int sub = 0; sub < 4; sub++) kn2v[sub] = skn2[half][16 * sub + lc];
        f32x4 d[4];
        const f32x4 z = {0.f, 0.f, 0.f, 0.f};
#pragma unroll
        for (int sub = 0; sub < 4; sub++) {
            s16x8 kh = *(s16x8*)&u.s.Kh[half][16 * sub + lc][g8];
            s16x8 kl = *(s16x8*)&u.s.Kl[half][16 * sub + lc][g8];
            f32x4 dd = __builtin_amdgcn_mfma_f32_16x16x32_bf16(qh, kl, z, 0, 0, 0);
            dd = __builtin_amdgcn_mfma_f32_16x16x32_bf16(ql, kh, dd, 0, 0, 0);
            dd = __builtin_amdgcn_mfma_f32_16x16x32_bf16(qh, kh, dd, 0, 0, 0);
            d[sub] = dd;
        }

        // ---- scores + online softmax (row stats via DPP) ----
#pragma unroll
        for (int r = 0; r < 4; r++) {
            float sc[4];
#pragma unroll
            for (int sub = 0; sub < 4; sub++) {
                float dd = d[sub][r];
                float w = fmaxf(fmaf(-dd, dd, qn2r[r] * kn2v[sub]), 0.f);
                sc[sub] = (dd - w) * CSC;
            }
            float lm = fmaxf(fmaxf(sc[0], sc[1]), fmaxf(sc[2], sc[3]));
            float rm = row_reduce_max(lm);
            float nm = fmaxf(m[r], rm);
            float al = __builtin_amdgcn_exp2f(m[r] - nm);  // 0 on first tile
            m[r] = nm;
            float p0 = __builtin_amdgcn_exp2f(sc[0] - nm);
            float p1 = __builtin_amdgcn_exp2f(sc[1] - nm);
            float p2 = __builtin_amdgcn_exp2f(sc[2] - nm);
            float p3 = __builtin_amdgcn_exp2f(sc[3] - nm);
            float rs = row_reduce_add(((p0 + p1) + (p2 + p3)));
            l[r] = fmaf(l[r], al, rs);
            acc0[r] *= al;
            acc1[r] *= al;
            // P in permuted-k order: key 16*sub+lc -> column 4*lc+sub
            *(uint2*)&sP[wave][4 * g + r][4 * lc] = make_uint2(pk2(p0, p1), pk2(p2, p3));
        }
        __builtin_amdgcn_s_waitcnt(0xC07F);  // lgkmcnt(0): P visible to own wave

        // ---- PV (k-dimension permuted consistently in sP and Vt) ----
        s16x8 pa0 = *(s16x8*)&sP[wave][lc][g8];
        s16x8 pa1 = *(s16x8*)&sP[wave][lc][32 + g8];
        s16x8 vb00 = *(s16x8*)&u.s.Vt[half][lc][g8];
        s16x8 vb01 = *(s16x8*)&u.s.Vt[half][lc][32 + g8];
        s16x8 vb10 = *(s16x8*)&u.s.Vt[half][lc + 16][g8];
        s16x8 vb11 = *(s16x8*)&u.s.Vt[half][lc + 16][32 + g8];
        acc0 = __builtin_amdgcn_mfma_f32_16x16x32_bf16(pa0, vb00, acc0, 0, 0, 0);
        acc0 = __builtin_amdgcn_mfma_f32_16x16x32_bf16(pa1, vb01, acc0, 0, 0, 0);
        acc1 = __builtin_amdgcn_mfma_f32_16x16x32_bf16(pa0, vb10, acc1, 0, 0, 0);
        acc1 = __builtin_amdgcn_mfma_f32_16x16x32_bf16(pa1, vb11, acc1, 0, 0, 0);

        __syncthreads();  // compute done before next staging overwrite
    }

    // ---- write per-wave partials (staging LDS reused) ----
#pragma unroll
    for (int r = 0; r < 4; r++) {
        u.c.acc[wave][4 * g + r][lc] = acc0[r];
        u.c.acc[wave][4 * g + r][lc + 16] = acc1[r];
    }
    if (lc == 0) {
#pragma unroll
        for (int r = 0; r < 4; r++) {
            u.c.m[wave][4 * g + r] = m[r];
            u.c.l[wave][4 * g + r] = l[r];
        }
    }
    __syncthreads();

    // ---- combine the two key-halves; thread = (query T>>3, d-quad T&7) ----
    const int q = T >> 3, dq = (T & 7) * 4, qr = q & 15;
    const int w0 = q >> 4, w1 = w0 + 4;
    float m0 = u.c.m[w0][qr], m1 = u.c.m[w1][qr];
    float l0 = u.c.l[w0][qr], l1 = u.c.l[w1][qr];
    float mf = fmaxf(m0, m1);
    float e0 = __builtin_amdgcn_exp2f(m0 - mf);
    float e1 = __builtin_amdgcn_exp2f(m1 - mf);
    float inv = 1.f / fmaf(l1, e1, l0 * e0);
    e0 *= inv;
    e1 *= inv;
    float4 o;
    o.x = u.c.acc[w0][qr][dq + 0] * e0 + u.c.acc[w1][qr][dq + 0] * e1;
    o.y = u.c.acc[w0][qr][dq + 1] * e0 + u.c.acc[w1][qr][dq + 1] * e1;
    o.z = u.c.acc[w0][qr][dq + 2] * e0 + u.c.acc[w1][qr][dq + 2] * e1;
    o.w = u.c.acc[w0][qr][dq + 3] * e0 + u.c.acc[w1][qr][dq + 3] * e1;
    *(float4*)(O + ((size_t)((b * NL + qt * 64 + q) * NH + h)) * ND + dq) = o;
}

extern "C" void kernel_launch(void* const* d_in, const int* in_sizes, int n_in,
                              void* d_out, int out_size, void* d_ws, size_t ws_size,
                              hipStream_t stream) {
    const float* Q = (const float*)d_in[0];
    const float* K = (const float*)d_in[1];
    const float* V = (const float*)d_in[2];
    float* O = (float*)d_out;
    geom_attn<<<NB * NH * (NL / 64), 512, 0, stream>>>(Q, K, V, O);
}

// Round 4
// 133.965 us; speedup vs baseline: 4.9225x; 1.0187x over previous
//
#include <hip/hip_runtime.h>
#include <hip/hip_bf16.h>
#include <math.h>

// GeomAttention: B=2, L=S=2048, H=8, E=D=32, fp32 in/out.
// scores = (0.5*dot - 0.5*relu(qn2*kn2 - dot^2))/sqrt(E); softmax over S; out = attn @ V.
// Transposed-dataflow MFMA flash attention: S^T = K·Q^T (C[key][query]) so softmax rows
// are in-lane; O^T = V^T·P^T. XOR-swizzled pad-free LDS (all accesses <=2-way => free).

#define NB 2
#define NL 2048
#define NS 2048
#define NH 8
#define NE 32
#define ND 32
#define KT 64
#define HK 1024            // keys per half-block sweep
#define NTILE (HK / KT)    // 16
#define CSC 0.12751742f    // 0.5 / sqrt(32) * log2(e)

typedef float f32x4 __attribute__((ext_vector_type(4)));
typedef short s16x8 __attribute__((ext_vector_type(8)));
typedef unsigned short u16;

__device__ inline unsigned pk2(float a, float b) {  // bf16(a) | bf16(b)<<16, RNE
    __hip_bfloat162 t = __float22bfloat162_rn(make_float2(a, b));
    union { __hip_bfloat162 h; unsigned u; } cv;
    cv.h = t;
    return cv.u;
}
template <int CTRL>
__device__ inline float dpp_add(float x) {
    return x + __int_as_float(__builtin_amdgcn_mov_dpp(__float_as_int(x), CTRL, 0xF, 0xF, false));
}
// swizzles (chunk = 8 u16 = 16 B)
__device__ inline int swzK(int row) { return (row ^ (row >> 2)) & 3; }   // 4-chunk rows
__device__ inline int swzV(int row) { return (row + (row >> 3)) & 7; }   // 8-chunk rows
__device__ inline int swzP(int row) { return row & 7; }                  // 8-chunk rows

__global__ __launch_bounds__(512, 4) void geom_attn(
    const float* __restrict__ Q, const float* __restrict__ K,
    const float* __restrict__ V, float* __restrict__ O) {
    __shared__ union {
        struct {
            u16 Kh[2][KT][32];    // [half][key][e]   rows 16 dw, swizzled chunks
            u16 Kl[2][KT][32];
            u16 Vt[2][ND][KT];    // [half][d][key]   rows 32 dw, swizzled
            float kn2[2][KT];
        } s;
        struct {
            float acc[8][32][17];  // [wave][d][q] (+1 pad)
            float m[8][16];
            float l[8][16];
        } c;
    } u;
    __shared__ u16 sP[8][16][KT];  // per-wave P^T rows [q][key], swizzled

    const int T = threadIdx.x;
    const int lane = T & 63, wave = T >> 6;
    const int g = lane >> 4, lc = lane & 15, g8 = g * 8;
    const int half = wave >> 2;
    const int qt = blockIdx.x & 31;
    const int bh = blockIdx.x >> 5;
    const int b = bh >> 3, h = bh & 7;
    const int qw = qt * 64 + (wave & 3) * 16;

    // ---- Q fragments (B-operand; hi/lo bf16) + exact qn2, all in-lane ----
    const float* qrow = Q + ((size_t)((b * NL + qw + lc) * NH + h)) * NE + g8;
    float4 qa = *(const float4*)qrow, qb = *(const float4*)(qrow + 4);
    float q8[8] = {qa.x, qa.y, qa.z, qa.w, qb.x, qb.y, qb.z, qb.w};
    union { unsigned u4[4]; s16x8 v; } qh_, ql_;
    float qn2 = 0.f;
#pragma unroll
    for (int i = 0; i < 4; i++) {
        float x0 = q8[2 * i], x1 = q8[2 * i + 1];
        qn2 = fmaf(x0, x0, qn2);
        qn2 = fmaf(x1, x1, qn2);
        unsigned h01 = pk2(x0, x1);
        qh_.u4[i] = h01;
        float h0 = __uint_as_float(h01 << 16);
        float h1 = __uint_as_float(h01 & 0xffff0000u);
        ql_.u4[i] = pk2(x0 - h0, x1 - h1);
    }
    const s16x8 qh = qh_.v, ql = ql_.v;
    qn2 += __shfl_xor(qn2, 16);
    qn2 += __shfl_xor(qn2, 32);   // full row-norm^2 of query lc, in every lane

    // ---- staging roles (256 threads per half) ----
    const int Tl = T & 255;
    const int sk = Tl >> 2, kc = Tl & 3;     // K: row sk, chunk kc (8 floats)
    const int dv = Tl & 31, vc = Tl >> 5;    // V: d-row dv, key-chunk vc (8 keys)
    const float* kbase = K + ((size_t)(b * NS * NH) + h) * NE;
    const float* vbase = V + ((size_t)(b * NS * NH) + h) * ND;
    const int kphys = (kc ^ swzK(sk)) * 8;
    const int vphys = (vc ^ swzV(dv)) * 8;

    // ---- prefetch tile 0 ----
    int s0 = half * HK;
    float4 ka = *(const float4*)(kbase + (size_t)(s0 + sk) * 256 + kc * 8);
    float4 kb = *(const float4*)(kbase + (size_t)(s0 + sk) * 256 + kc * 8 + 4);
    float vr[8];
#pragma unroll
    for (int i = 0; i < 8; i++) vr[i] = vbase[(size_t)(s0 + 8 * vc + i) * 256 + dv];

    f32x4 acc0 = {0.f, 0.f, 0.f, 0.f}, acc1 = {0.f, 0.f, 0.f, 0.f};
    float m = -INFINITY, l = 0.f;

    for (int t = 0; t < NTILE; ++t) {
        // ---- stage tile t: cvt + swizzled LDS writes + fused kn2 ----
        {
            float kx[8] = {ka.x, ka.y, ka.z, ka.w, kb.x, kb.y, kb.z, kb.w};
            unsigned hh[4], ll[4];
            float kn2p = 0.f;
#pragma unroll
            for (int i = 0; i < 4; i++) {
                float x0 = kx[2 * i], x1 = kx[2 * i + 1];
                kn2p = fmaf(x0, x0, kn2p);
                kn2p = fmaf(x1, x1, kn2p);
                unsigned h01 = pk2(x0, x1);
                hh[i] = h01;
                float h0 = __uint_as_float(h01 << 16);
                float h1 = __uint_as_float(h01 & 0xffff0000u);
                ll[i] = pk2(x0 - h0, x1 - h1);
            }
            *(uint4*)&u.s.Kh[half][sk][kphys] = make_uint4(hh[0], hh[1], hh[2], hh[3]);
            *(uint4*)&u.s.Kl[half][sk][kphys] = make_uint4(ll[0], ll[1], ll[2], ll[3]);
            kn2p = dpp_add<0xB1>(kn2p);   // quad reduce: 4 chunk-threads per K row
            kn2p = dpp_add<0x4E>(kn2p);
            if (kc == 0) u.s.kn2[half][sk] = kn2p;
            *(uint4*)&u.s.Vt[half][dv][vphys] =
                make_uint4(pk2(vr[0], vr[1]), pk2(vr[2], vr[3]),
                           pk2(vr[4], vr[5]), pk2(vr[6], vr[7]));
        }
        // ---- prefetch tile t+1 ----
        const int tn = (t + 1 < NTILE) ? t + 1 : t;
        const int sn = half * HK + tn * KT;
        ka = *(const float4*)(kbase + (size_t)(sn + sk) * 256 + kc * 8);
        kb = *(const float4*)(kbase + (size_t)(sn + sk) * 256 + kc * 8 + 4);
#pragma unroll
        for (int i = 0; i < 8; i++) vr[i] = vbase[(size_t)(sn + 8 * vc + i) * 256 + dv];

        __syncthreads();

        // ---- S^T = K·Q^T: 4 key-subtiles x 3-MFMA hi/lo (A=K from LDS, B=Q regs) ----
        f32x4 d[4], kn2v[4];
        const f32x4 z = {0.f, 0.f, 0.f, 0.f};
        const int skr = swzK(lc);  // swzK(16*st+lc) == swzK(lc)
#pragma unroll
        for (int st = 0; st < 4; st++) {
            kn2v[st] = *(f32x4*)&u.s.kn2[half][16 * st + 4 * g];
            s16x8 kh = *(s16x8*)&u.s.Kh[half][16 * st + lc][(g ^ skr) * 8];
            s16x8 kl = *(s16x8*)&u.s.Kl[half][16 * st + lc][(g ^ skr) * 8];
            f32x4 dd = __builtin_amdgcn_mfma_f32_16x16x32_bf16(kl, qh, z, 0, 0, 0);
            dd = __builtin_amdgcn_mfma_f32_16x16x32_bf16(kh, ql, dd, 0, 0, 0);
            dd = __builtin_amdgcn_mfma_f32_16x16x32_bf16(kh, qh, dd, 0, 0, 0);
            d[st] = dd;   // C[key=16st+4g+r][query=lc]
        }

        // ---- scores (log2 domain), all 16 values for query lc in-lane ----
        float sc[4][4];
#pragma unroll
        for (int st = 0; st < 4; st++)
#pragma unroll
            for (int r = 0; r < 4; r++) {
                float dd = d[st][r];
                float w = fmaxf(fmaf(-dd, dd, qn2 * kn2v[st][r]), 0.f);
                sc[st][r] = (dd - w) * CSC;
            }

        // ---- online softmax: in-lane tree max + 2 shuffles; 1 alpha/lane ----
        float t0 = fmaxf(fmaxf(sc[0][0], sc[0][1]), fmaxf(sc[0][2], sc[0][3]));
        float t1 = fmaxf(fmaxf(sc[1][0], sc[1][1]), fmaxf(sc[1][2], sc[1][3]));
        float t2 = fmaxf(fmaxf(sc[2][0], sc[2][1]), fmaxf(sc[2][2], sc[2][3]));
        float t3 = fmaxf(fmaxf(sc[3][0], sc[3][1]), fmaxf(sc[3][2], sc[3][3]));
        float tm = fmaxf(fmaxf(t0, t1), fmaxf(t2, t3));
        tm = fmaxf(tm, __shfl_xor(tm, 16));
        tm = fmaxf(tm, __shfl_xor(tm, 32));
        const float nm = fmaxf(m, tm);
        const float al = __builtin_amdgcn_exp2f(m - nm);  // 0 on first tile
        m = nm;
        float p[4][4], ls = 0.f;
#pragma unroll
        for (int st = 0; st < 4; st++) {
#pragma unroll
            for (int r = 0; r < 4; r++) {
                p[st][r] = __builtin_amdgcn_exp2f(sc[st][r] - nm);
                ls += p[st][r];
            }
        }
        l = fmaf(l, al, ls);
        acc0 *= al;
        acc1 *= al;

        // ---- P^T into per-wave LDS (swizzled b64 writes), then PV MFMAs ----
#pragma unroll
        for (int st = 0; st < 4; st++) {
            const int chunkl = 2 * st + (g >> 1);
            const int off = (chunkl ^ swzP(lc)) * 8 + (g & 1) * 4;
            *(uint2*)&sP[wave][lc][off] =
                make_uint2(pk2(p[st][0], p[st][1]), pk2(p[st][2], p[st][3]));
        }
        __builtin_amdgcn_s_waitcnt(0xC07F);  // lgkmcnt(0): own-wave sP visible

        const int svl = swzV(lc), svh = swzV(lc + 16), spl = swzP(lc);
        s16x8 va00 = *(s16x8*)&u.s.Vt[half][lc][(g ^ svl) * 8];
        s16x8 va01 = *(s16x8*)&u.s.Vt[half][lc][((4 + g) ^ svl) * 8];
        s16x8 va10 = *(s16x8*)&u.s.Vt[half][lc + 16][(g ^ svh) * 8];
        s16x8 va11 = *(s16x8*)&u.s.Vt[half][lc + 16][((4 + g) ^ svh) * 8];
        s16x8 pb0 = *(s16x8*)&sP[wave][lc][(g ^ spl) * 8];
        s16x8 pb1 = *(s16x8*)&sP[wave][lc][((4 + g) ^ spl) * 8];
        acc0 = __builtin_amdgcn_mfma_f32_16x16x32_bf16(va00, pb0, acc0, 0, 0, 0);
        acc0 = __builtin_amdgcn_mfma_f32_16x16x32_bf16(va01, pb1, acc0, 0, 0, 0);
        acc1 = __builtin_amdgcn_mfma_f32_16x16x32_bf16(va10, pb0, acc1, 0, 0, 0);
        acc1 = __builtin_amdgcn_mfma_f32_16x16x32_bf16(va11, pb1, acc1, 0, 0, 0);

        __syncthreads();  // all reads done before next staging overwrite
    }

    // ---- epilogue: finish l, publish per-wave partials, combine halves ----
    l += __shfl_xor(l, 16);
    l += __shfl_xor(l, 32);
#pragma unroll
    for (int r = 0; r < 4; r++) {
        u.c.acc[wave][4 * g + r][lc] = acc0[r];       // O^T[d][q]
        u.c.acc[wave][16 + 4 * g + r][lc] = acc1[r];
    }
    if (lane < 16) {
        u.c.m[wave][lc] = m;
        u.c.l[wave][lc] = l;
    }
    __syncthreads();

    const int q = T >> 3, dq = (T & 7) * 4, qr = q & 15;
    const int w0 = q >> 4, w1 = w0 + 4;
    float m0 = u.c.m[w0][qr], m1 = u.c.m[w1][qr];
    float l0 = u.c.l[w0][qr], l1 = u.c.l[w1][qr];
    float mf = fmaxf(m0, m1);
    float e0 = __builtin_amdgcn_exp2f(m0 - mf);
    float e1 = __builtin_amdgcn_exp2f(m1 - mf);
    float inv = 1.f / fmaf(l1, e1, l0 * e0);
    e0 *= inv;
    e1 *= inv;
    float4 o;
    o.x = u.c.acc[w0][dq + 0][qr] * e0 + u.c.acc[w1][dq + 0][qr] * e1;
    o.y = u.c.acc[w0][dq + 1][qr] * e0 + u.c.acc[w1][dq + 1][qr] * e1;
    o.z = u.c.acc[w0][dq + 2][qr] * e0 + u.c.acc[w1][dq + 2][qr] * e1;
    o.w = u.c.acc[w0][dq + 3][qr] * e0 + u.c.acc[w1][dq + 3][qr] * e1;
    *(float4*)(O + ((size_t)((b * NL + qt * 64 + q) * NH + h)) * ND + dq) = o;
}

extern "C" void kernel_launch(void* const* d_in, const int* in_sizes, int n_in,
                              void* d_out, int out_size, void* d_ws, size_t ws_size,
                              hipStream_t stream) {
    const float* Q = (const float*)d_in[0];
    const float* K = (const float*)d_in[1];
    const float* V = (const float*)d_in[2];
    float* O = (float*)d_out;
    geom_attn<<<NB * NH * (NL / 64), 512, 0, stream>>>(Q, K, V, O);
}